// Round 2
// baseline (361.497 us; speedup 1.0000x reference)
//
#include <hip/hip_runtime.h>
#include <stdint.h>

#define HW        (1024 * 1024)
#define KIDS      64
#define NCANDS    16
#define BCC       76          /* B*C = 4*19 */
#define EPSF      1e-6f
#define MARGINF   1.0f
#define SENT      0xFFFFFFFFu

// ---------------- Threefry-2x32 (exact JAX schedule, partitionable PRNG) ----
__host__ __device__ constexpr uint32_t rotl32c(uint32_t v, int r) {
    return (v << r) | (v >> (32 - r));
}

__host__ __device__ constexpr uint64_t tf2x32(uint32_t k0, uint32_t k1,
                                              uint32_t x0, uint32_t x1) {
    const uint32_t ks2 = k0 ^ k1 ^ 0x1BD11BDAu;
    const int R0[4] = {13, 15, 26, 6};
    const int R1[4] = {17, 29, 16, 24};
    x0 += k0; x1 += k1;
    for (int i = 0; i < 4; i++) { x0 += x1; x1 = rotl32c(x1, R0[i]); x1 ^= x0; }
    x0 += k1; x1 += ks2 + 1u;
    for (int i = 0; i < 4; i++) { x0 += x1; x1 = rotl32c(x1, R1[i]); x1 ^= x0; }
    x0 += ks2; x1 += k0 + 2u;
    for (int i = 0; i < 4; i++) { x0 += x1; x1 = rotl32c(x1, R0[i]); x1 ^= x0; }
    x0 += k0; x1 += k1 + 3u;
    for (int i = 0; i < 4; i++) { x0 += x1; x1 = rotl32c(x1, R1[i]); x1 ^= x0; }
    x0 += k1; x1 += ks2 + 4u;
    for (int i = 0; i < 4; i++) { x0 += x1; x1 = rotl32c(x1, R0[i]); x1 ^= x0; }
    x0 += ks2; x1 += k0 + 5u;
    return ((uint64_t)x0 << 32) | x1;
}

// split(key(1))[1] — compile-time constant child key.
constexpr uint64_t SPLIT1 = tf2x32(0u, 1u, 0u, 1u);
constexpr uint32_t K2A = (uint32_t)(SPLIT1 >> 32);
constexpr uint32_t K2B = (uint32_t)SPLIT1;

// 32-bit random word j of random_bits(k2, (64,16)): xor of the two halves.
__device__ __forceinline__ uint32_t jax_cand_bits(uint32_t j) {
    const uint64_t r = tf2x32(K2A, K2B, 0u, j);
    return (uint32_t)(r >> 32) ^ (uint32_t)r;
}

// ---------------- kernels ---------------------------------------------------
__global__ void k_init(uint32_t* g_first, uint32_t* g_second,
                       float* g_total, int* g_cnt, int* g_done) {
    const int t = threadIdx.x;
    if (t < KIDS) { g_first[t] = SENT; g_second[t] = SENT; }
    if (t == 0)   { *g_total = 0.0f; *g_cnt = 0; *g_done = 0; }
}

// One pass over the mask. Per-pixel displaced-value trick in LDS:
//   old = atomicMin(m1[id], pix); atomicMin(m2[id], max(old, pix))
// The multiset of displaced values is exactly all inserted pixels except the
// final minimum, so m2 ends as the block's second-smallest. Same trick merges
// block results into global (linearizable device-scope atomics).
__global__ __launch_bounds__(256) void
k_seg(const int* __restrict__ mask, uint32_t* g_first, uint32_t* g_second) {
    __shared__ uint32_t m1[KIDS], m2[KIDS];
    const int t = threadIdx.x;
    if (t < KIDS) { m1[t] = SENT; m2[t] = SENT; }
    __syncthreads();

    const int4* m4 = (const int4*)mask;
    const int base4 = blockIdx.x * 1024;   // 4096 pixels / block, int4 units
#pragma unroll
    for (int c = 0; c < 4; c++) {
        const int4 v = m4[base4 + c * 256 + t];
        const uint32_t pix0 = (uint32_t)(base4 + c * 256 + t) * 4u;
        const int ids[4] = {v.x, v.y, v.z, v.w};
#pragma unroll
        for (int j = 0; j < 4; j++) {
            const uint32_t pix = pix0 + j;
            const uint32_t old = atomicMin(&m1[ids[j]], pix);
            const uint32_t disp = old > pix ? old : pix;
            if (disp != SENT) atomicMin(&m2[ids[j]], disp);
        }
    }
    __syncthreads();

    if (t < KIDS && m1[t] != SENT) {
        const uint32_t lm1 = m1[t];
        const uint32_t old = atomicMin(&g_first[t], lm1);
        const uint32_t disp = old > lm1 ? old : lm1;
        if (disp != SENT)  atomicMin(&g_second[t], disp);
        if (m2[t] != SENT) atomicMin(&g_second[t], m2[t]);
    }
}

// One block per id: parallel negative pick, gather 3x76-dim columns, reduce,
// hinge, accumulate. Last-arriving block (device-scope done counter) writes
// the final mean — no separate finalize kernel.
__global__ __launch_bounds__(128) void
k_triplet(const float* __restrict__ sem, const int* __restrict__ mask,
          const uint32_t* __restrict__ g_first,
          const uint32_t* __restrict__ g_second,
          float* g_total, int* g_cnt, int* g_done, float* out) {
    const int k = blockIdx.x;
    const int t = threadIdx.x;
    const uint32_t f = g_first[k], s = g_second[k];
    const bool valid = (k != 0) && (s < (uint32_t)HW);   // block-uniform

    __shared__ int s_neg;
    __shared__ float red_ap[128], red_an[128];

    if (valid) {
        if (t < 64) {                       // wave 0 picks the negative
            uint32_t cand = 0; bool ok = false;
            if (t < NCANDS) {
                cand = jax_cand_bits((uint32_t)(k * NCANDS + t)) & (HW - 1);
                ok = (mask[cand] != k);
            }
            const unsigned long long bal = __ballot(ok);
            const int pick = bal ? (__ffsll(bal) - 1) : 0;  // argmax semantics
            const int neg = __shfl((int)cand, pick);
            if (t == 0) s_neg = neg;
        }
        __syncthreads();

        const int n = s_neg;
        float ap = 0.0f, an = 0.0f;
        if (t < BCC) {
            const size_t row = (size_t)t * (size_t)HW;
            const float a  = sem[row + f];
            const float p  = sem[row + s];
            const float nn = sem[row + n];
            const float d1 = a - p + EPSF;
            const float d2 = a - nn + EPSF;
            ap = d1 * d1; an = d2 * d2;
        }
        red_ap[t] = ap; red_an[t] = an;
        __syncthreads();
        for (int off = 64; off > 0; off >>= 1) {
            if (t < off) { red_ap[t] += red_ap[t + off]; red_an[t] += red_an[t + off]; }
            __syncthreads();
        }
        if (t == 0) {
            float per = sqrtf(red_ap[0]) - sqrtf(red_an[0]) + MARGINF;
            per = per > 0.0f ? per : 0.0f;
            atomicAdd(g_total, per);
            atomicAdd(g_cnt, 1);
        }
    }

    __threadfence();                        // release our adds before done++
    if (t == 0) {
        const int done = atomicAdd(g_done, 1);
        if (done == KIDS - 1) {             // last block finalizes
            const float total = atomicAdd(g_total, 0.0f);  // coherent read
            const int   cnt   = atomicAdd(g_cnt, 0);
            out[0] = (cnt > 0) ? (total / (float)cnt) : 0.0f;
        }
    }
}

extern "C" void kernel_launch(void* const* d_in, const int* in_sizes, int n_in,
                              void* d_out, int out_size, void* d_ws, size_t ws_size,
                              hipStream_t stream) {
    const float* sem  = (const float*)d_in[0];   // [4,19,1024,1024] f32
    const int*   mask = (const int*)d_in[1];     // [1024,1024] i32
    float* out = (float*)d_out;

    uint32_t* ws = (uint32_t*)d_ws;
    uint32_t* g_first  = ws;                 // 64
    uint32_t* g_second = ws + 64;            // 64
    float*    g_total  = (float*)(ws + 128);
    int*      g_cnt    = (int*)(ws + 129);
    int*      g_done   = (int*)(ws + 130);

    k_init<<<1, 64, 0, stream>>>(g_first, g_second, g_total, g_cnt, g_done);
    k_seg<<<HW / 4096, 256, 0, stream>>>(mask, g_first, g_second);
    k_triplet<<<KIDS, 128, 0, stream>>>(sem, mask, g_first, g_second,
                                        g_total, g_cnt, g_done, out);
}